// Round 7
// baseline (112.836 us; speedup 1.0000x reference)
//
#include <hip/hip_runtime.h>
#include <hip/hip_fp16.h>

// Problem constants (from reference): B=1024, D_IN=64, D_HID=128.
#define BB      1024
#define DIN     64
#define DHID    128
#define NPAIRS  (1024.0f * 1024.0f)
#define BN_EPS  1e-5f

// Native packed-fp16 vector type: clang emits v_pk_{add,mul,fma,max}_f16
// for operators / __builtin_elementwise_max on this type.
typedef _Float16 h2 __attribute__((ext_vector_type(2)));

struct __align__(16) H24 { h2 h[4]; };
struct __align__(8)  H22 { h2 lo, hi; };   // one ds_read_b64

__device__ __forceinline__ h2 mk_h2(float a, float b) {
    h2 r; r.x = (_Float16)a; r.y = (_Float16)b; return r;
}

__device__ __forceinline__ unsigned short h2bits(_Float16 h) {
    return __builtin_bit_cast(unsigned short, h);
}
// monotone map: fp16 bits -> u16 order key (total order; only +0/-0 collide
// numerically, and exact-tie elements contribute (z+v)=0 to both stats sums,
// so either inclusion is exact).
__device__ __forceinline__ unsigned short ord16(unsigned short b) {
    return (b & 0x8000u) ? (unsigned short)~b : (unsigned short)(b | 0x8000u);
}

// ---------------------------------------------------------------------------
// Round-12 structure: 3 kernels.
//   K1  proj:   U,V projections (round-10 version: Uph replicated + Up3/Vp3
//               channel-major pairs).
//   K2h stats:  EXACT per-channel BN stats in O(B) via fp16 counting-sort
//               buckets. Replaces brute K2 (~11us) + K2b (~1.5us).
//               Closed form (verified passing in round-10):
//                 sum_j relu(z+v_j)   = n*z + S1
//                 sum_j relu(z+v_j)^2 = n*z^2 + 2*z*S1 + S2
//               over the suffix {v_j > -z}. Suffix resolved per-i as
//               bucket-table lookup + short boundary-bucket scan.
//               ~20 barriers total (round-10's sort version had ~75 -> 20us;
//               that was the failure, not the math).
//   K3  out:    unchanged measured-good output pass (round-11 version).
// Dead ends (measured): coop grid.sync ~100us/sync; single-block tails over
// cross-XCD partials +20..+36us; occupancy/grid changes on K2/K3 ~0;
// K3 LDS micro-opts ~0.
// ---------------------------------------------------------------------------

// K1: U[i][c] = x[i,:] . W1[0:64, c] + b1[c];  V[j][c] = x[j,:] . W1[64:, c]
//   Uph[i*128+c]   = h2(u,u)             (replicated, for K3's pk_add)
//   Up3[c*512+ip]  = h2(u_2ip, u_2ip+1)  (c-major, for K2h)
//   Vp3[c*512+jp]  = h2(v_2jp, v_2jp+1)  (c-major, for K2h + K3)
__global__ __launch_bounds__(256) void k1_proj(
    const float* __restrict__ x, const float* __restrict__ W1,
    const float* __restrict__ b1,
    h2* __restrict__ Uph, h2* __restrict__ Up3, h2* __restrict__ Vp3)
{
    __shared__ float xs[4][DIN];
    const int c     = threadIdx.x & 127;
    const int hf    = threadIdx.x >> 7;      // 0..1
    const int rbase = blockIdx.x * 4;

    xs[threadIdx.x >> 6][threadIdx.x & 63] = x[rbase * DIN + threadIdx.x];
    __syncthreads();

    float u0 = 0.f, u1 = 0.f, v0 = 0.f, v1 = 0.f;
    const int r0 = hf * 2;
    #pragma unroll 8
    for (int k = 0; k < DIN; ++k) {
        const float wt = W1[k * DHID + c];          // coalesced over c
        const float wb = W1[(DIN + k) * DHID + c];
        const float x0 = xs[r0][k];                  // LDS broadcast
        const float x1 = xs[r0 + 1][k];
        u0 = fmaf(x0, wt, u0); v0 = fmaf(x0, wb, v0);
        u1 = fmaf(x1, wt, u1); v1 = fmaf(x1, wb, v1);
    }
    const float bbv = b1[c];
    const int row0 = rbase + r0;                     // even
    Uph[row0 * DHID + c]       = mk_h2(u0 + bbv, u0 + bbv);
    Uph[(row0 + 1) * DHID + c] = mk_h2(u1 + bbv, u1 + bbv);
    const int p = row0 >> 1;
    Up3[c * (BB / 2) + p] = mk_h2(u0 + bbv, u1 + bbv);  // scattered, 256 KB
    Vp3[c * (BB / 2) + p] = mk_h2(v0, v1);              // scattered, 256 KB
}

// K2h: exact per-channel BN stats via 256-bucket counting sort on fp16 keys.
// Grid: 128 blocks (one channel each) x 256 threads (4 elems/thread).
__global__ __launch_bounds__(256) void k2h_stats(
    const h2* __restrict__ Up3, const h2* __restrict__ Vp3,
    float* __restrict__ sums)
{
    __shared__ unsigned int   hist[256];              // per-bucket count (kept)
    __shared__ unsigned int   pcA[256], pcB[256];     // count prefix ping-pong
    __shared__ float          s1A[256], s1B[256];     // sum(v) aggregates/prefix
    __shared__ float          s2A[256], s2B[256];     // sum(v^2)
    __shared__ unsigned short sord[1024];             // bucket-sorted order keys
    __shared__ float          sval[1024];             // bucket-sorted values

    const int c   = blockIdx.x;          // 0..127
    const int tid = threadIdx.x;

    // issue all global loads up front (latency overlap with LDS init)
    const h2 va = Vp3[c * 512 + tid];
    const h2 vb = Vp3[c * 512 + 256 + tid];
    const h2 ua = Up3[c * 512 + tid];
    const h2 ub = Up3[c * 512 + 256 + tid];

    hist[tid] = 0u; s1A[tid] = 0.f; s2A[tid] = 0.f;
    __syncthreads();

    // histogram + per-bucket aggregates + intra-bucket slot reservation
    unsigned short ordv[4]; unsigned int pos[4]; float vf[4];
    { 
        const _Float16 vh[4] = {va.x, va.y, vb.x, vb.y};
        #pragma unroll
        for (int q = 0; q < 4; ++q) {
            const unsigned short o = ord16(h2bits(vh[q]));
            const float f = (float)vh[q];
            ordv[q] = o; vf[q] = f;
            const unsigned int hb = o >> 8;
            pos[q] = atomicAdd(&hist[hb], 1u);
            atomicAdd(&s1A[hb], f);
            atomicAdd(&s2A[hb], f * f);
        }
    }
    __syncthreads();

    // joint inclusive prefix scan over buckets: (count, S1, S2), ping-pong.
    pcA[tid] = hist[tid];
    __syncthreads();
    unsigned int* pin = pcA; unsigned int* pout = pcB;
    float* ain = s1A; float* aout = s1B;
    float* bin = s2A; float* bout = s2B;
    #pragma unroll
    for (int s = 1; s < 256; s <<= 1) {
        const unsigned int cadd = (tid >= s) ? pin[tid - s] : 0u;
        const float f1 = (tid >= s) ? ain[tid - s] : 0.f;
        const float f2 = (tid >= s) ? bin[tid - s] : 0.f;
        pout[tid] = pin[tid] + cadd;
        aout[tid] = ain[tid] + f1;
        bout[tid] = bin[tid] + f2;
        __syncthreads();
        unsigned int* tp = pin; pin = pout; pout = tp;
        float* t1 = ain; ain = aout; aout = t1;
        float* t2 = bin; bin = bout; bout = t2;
    }
    // results now in *pin/*ain/*bin (inclusive prefixes); hist[] = raw counts
    const float T1 = ain[255], T2 = bin[255];

    // scatter into bucket-sorted arrays
    #pragma unroll
    for (int q = 0; q < 4; ++q) {
        const unsigned int hb = ordv[q] >> 8;
        const unsigned int st = (hb ? pin[hb - 1] : 0u) + pos[q];
        sord[st] = ordv[q];
        sval[st] = vf[q];
    }
    __syncthreads();

    // per-i closed form, 4 i's per thread
    float accS = 0.f, accQ = 0.f;
    {
        const _Float16 uh[4] = {ua.x, ua.y, ub.x, ub.y};
        #pragma unroll
        for (int q = 0; q < 4; ++q) {
            const float z = (float)uh[q];
            const unsigned short tb = (unsigned short)(h2bits(uh[q]) ^ 0x8000u); // bits(-u)
            const unsigned short to = ord16(tb);
            const unsigned int hbt  = to >> 8;
            const unsigned int base = pin[hbt];          // #elems in buckets <= hbt
            float n  = (float)(1024u - base);
            float S1 = T1 - ain[hbt];
            float S2 = T2 - bin[hbt];
            // boundary bucket: exact low-bit resolution (avg 4 elems)
            for (unsigned int k = base - hist[hbt]; k < base; ++k) {
                if (sord[k] > to) {
                    const float vv = sval[k];
                    n += 1.f; S1 += vv; S2 += vv * vv;
                }
            }
            accS += fmaf(n, z, S1);
            accQ += fmaf(n * z, z, fmaf(2.f * z, S1, S2));
        }
    }
    __syncthreads();

    // block reduce 256 -> 1 (reuse the dead ping buffers)
    float* ra = aout; float* rb = bout;
    ra[tid] = accS; rb[tid] = accQ;
    __syncthreads();
    #pragma unroll
    for (int off = 128; off >= 1; off >>= 1) {
        if (tid < off) { ra[tid] += ra[tid + off]; rb[tid] += rb[tid + off]; }
        __syncthreads();
    }
    if (tid == 0) { sums[c] = ra[0]; sums[DHID + c] = rb[0]; }
}

// K3: out[i,j] = t + sum_c relu(U[i,c] + V[j,c]) * s[c], packed fp16.
// Grid: dim3(128, 8) = 1024 blocks, 4 blocks/CU. Block = 8 i x 128 j;
// thread = 2 i x 1 jpair (2 j). Inner per (i,jpair): pk_add+pk_max+pk_fma
// = 3 instr / 2 elements. fp16 accumulators flushed to fp32 every 32 c.
__global__ __launch_bounds__(256, 4) void k3_out(
    const h2* __restrict__ Uph, const h2* __restrict__ Vp3,
    const float* __restrict__ sums,
    const float* __restrict__ gamma, const float* __restrict__ beta,
    const float* __restrict__ W2, const float* __restrict__ b2,
    float* __restrict__ out)
{
    __shared__ __align__(16) h2 lutp[DHID][8];  // U packed, transposed [c][i]
    __shared__ h2    lsch[DHID];     // h2(s_c, s_c)
    __shared__ float ltp[DHID];
    __shared__ float lt;

    const int tid   = threadIdx.x;
    const int ib    = blockIdx.x * 8;     // gridDim.x = 128
    const int jbase = blockIdx.y * 128;   // gridDim.y = 8

    if (tid < DHID) {
        const float invN = 1.0f / NPAIRS;
        const float mean = sums[tid] * invN;
        const float var  = fmaxf(sums[DHID + tid] * invN - mean * mean, 0.f);
        const float inv  = rsqrtf(var + BN_EPS);
        const float gi   = gamma[tid] * inv;
        const float w2   = W2[tid];
        lsch[tid] = mk_h2(gi * w2, gi * w2);
        ltp[tid]  = (beta[tid] - mean * gi) * w2;
    }
    // stage 8 rows of packed U into LDS, transposed to [c][i]
    #pragma unroll
    for (int t = tid; t < 8 * DHID; t += 256)
        lutp[t & 127][t >> 7] = Uph[(ib + (t >> 7)) * DHID + (t & 127)];
    __syncthreads();
    // wave-0 shuffle reduction of ltp -> lt
    if (tid < 64) {
        float tl = ltp[tid] + ltp[tid + 64];
        #pragma unroll
        for (int off = 32; off >= 1; off >>= 1)
            tl += __shfl_down(tl, off, 64);
        if (tid == 0) lt = tl + b2[0];
    }
    __syncthreads();
    const float tconst = lt;

    const int i0   = (tid >> 6) * 2;              // 0,2,4,6 (wave-uniform)
    const int lane = tid & 63;
    const int jp0  = (jbase >> 1) + lane;         // 1 jpair = 2 j per lane

    const h2 zero2 = mk_h2(0.f, 0.f);
    h2 a00 = zero2, a10 = zero2;
    float2 f00 = {0.f, 0.f}, f10 = {0.f, 0.f};

    for (int cb = 0; cb < 4; ++cb) {
        #pragma unroll 8
        for (int ci = 0; ci < 32; ++ci) {
            const int c = cb * 32 + ci;
            const h2 v0  = Vp3[c * (BB / 2) + jp0];      // coalesced 4B/lane
            const h2 sc  = lsch[c];                      // LDS broadcast
            const H22 uu = *(const H22*)&lutp[c][i0];    // ONE ds_read_b64
            a00 = __builtin_elementwise_max(uu.lo + v0, zero2) * sc + a00;
            a10 = __builtin_elementwise_max(uu.hi + v0, zero2) * sc + a10;
        }
        f00.x += (float)a00.x; f00.y += (float)a00.y; a00 = zero2;
        f10.x += (float)a10.x; f10.y += (float)a10.y; a10 = zero2;
    }

    const int j0 = jbase + lane * 2;
    float2 o;
    o.x = f00.x + tconst; o.y = f00.y + tconst;
    *(float2*)&out[(ib + i0) * BB + j0] = o;
    o.x = f10.x + tconst; o.y = f10.y + tconst;
    *(float2*)&out[(ib + i0 + 1) * BB + j0] = o;
}

extern "C" void kernel_launch(void* const* d_in, const int* in_sizes, int n_in,
                              void* d_out, int out_size, void* d_ws, size_t ws_size,
                              hipStream_t stream) {
    const float* x     = (const float*)d_in[0];  // (1024, 64)
    const float* W1    = (const float*)d_in[1];  // (128, 128)
    const float* b1    = (const float*)d_in[2];  // (128,)
    const float* gamma = (const float*)d_in[3];  // (128,)
    const float* beta  = (const float*)d_in[4];  // (128,)
    const float* W2    = (const float*)d_in[5];  // (128,)
    const float* b2    = (const float*)d_in[6];  // (1,)
    float* out = (float*)d_out;                  // (1024*1024,)

    float* ws = (float*)d_ws;
    h2* Uph     = (h2*)ws;                       // 1024*128 h2 (512 KB)
    h2* Vp3     = (h2*)(ws + 131072);            // 128*512 h2 (256 KB)
    h2* Up3     = (h2*)(ws + 196608);            // 128*512 h2 (256 KB)
    float* sums = ws + 262144;                   // 256 (sum | sumsq)

    k1_proj<<<256, 256, 0, stream>>>(x, W1, b1, Uph, Up3, Vp3);
    k2h_stats<<<128, 256, 0, stream>>>(Up3, Vp3, sums);
    k3_out<<<dim3(128, 8), 256, 0, stream>>>(Uph, Vp3, sums, gamma, beta, W2, b2, out);
}

// Round 8
// 99.705 us; speedup vs baseline: 1.1317x; 1.1317x over previous
//
#include <hip/hip_runtime.h>
#include <hip/hip_fp16.h>

// Problem constants (from reference): B=1024, D_IN=64, D_HID=128.
#define BB      1024
#define DIN     64
#define DHID    128
#define NPAIRS  (1024.0f * 1024.0f)
#define BN_EPS  1e-5f

// Native packed-fp16 vector type: clang emits v_pk_{add,mul,fma,max}_f16
// for operators / __builtin_elementwise_max on this type.
typedef _Float16 h2 __attribute__((ext_vector_type(2)));

struct __align__(16) H24 { h2 h[4]; };
struct __align__(8)  H22 { h2 lo, hi; };   // one ds_read_b64

__device__ __forceinline__ h2 mk_h2(float a, float b) {
    h2 r; r.x = (_Float16)a; r.y = (_Float16)b; return r;
}

// dot2 with fp32 accumulator: a.x*b.x + a.y*b.y + acc (v_dot2_f32_f16).
__device__ __forceinline__ float fdot2acc(h2 a, h2 b, float acc) {
#if __has_builtin(__builtin_amdgcn_fdot2)
    return __builtin_amdgcn_fdot2(a, b, acc, false);
#else
    return acc + (float)a.x * (float)b.x + (float)a.y * (float)b.y;
#endif
}

// ---------------------------------------------------------------------------
// Round-13: baseline 4-kernel structure (measured 98.7 +- 0.5 over N=3),
// with ONE change: K2's inner loop drops the dot2(r,one) per-pair in favor
// of a packed-fp16 partial-sum accumulator flushed to fp32 once per 8-ii
// group: 16 -> 13 instr per (t,ii) = -18.75% VALU on the largest kernel.
// Numerics: flush chains hold <=8 values of magnitude <=~8 (fp16 exact to
// 0.0625 at 64) -> stats perturbation ~2e-5 relative, invisible vs the
// fp16-dominated output absmax.
// Dead ends (measured): coop grid.sync ~100us/sync; last-block tails
// +20..+36us; sort-stats +13.5us; bucket-stats +14us (gaussian-concentrated
// buckets serialize); occupancy/grid tweaks ~0; K3 LDS micro-opts ~0.
// ---------------------------------------------------------------------------

// K1: U[i][c] = x[i,:] . W1[0:64, c] + b1[c];  V[j][c] = x[j,:] . W1[64:, c]
__global__ __launch_bounds__(256) void k1_proj(
    const float* __restrict__ x, const float* __restrict__ W1,
    const float* __restrict__ b1,
    h2* __restrict__ Uph, h2* __restrict__ Vp2, h2* __restrict__ Vp3)
{
    __shared__ float xs[4][DIN];
    const int c     = threadIdx.x & 127;
    const int hf    = threadIdx.x >> 7;      // 0..1
    const int rbase = blockIdx.x * 4;

    xs[threadIdx.x >> 6][threadIdx.x & 63] = x[rbase * DIN + threadIdx.x];
    __syncthreads();

    float u0 = 0.f, u1 = 0.f, v0 = 0.f, v1 = 0.f;
    const int r0 = hf * 2;
    #pragma unroll 8
    for (int k = 0; k < DIN; ++k) {
        const float wt = W1[k * DHID + c];          // coalesced over c
        const float wb = W1[(DIN + k) * DHID + c];
        const float x0 = xs[r0][k];                  // LDS broadcast
        const float x1 = xs[r0 + 1][k];
        u0 = fmaf(x0, wt, u0); v0 = fmaf(x0, wb, v0);
        u1 = fmaf(x1, wt, u1); v1 = fmaf(x1, wb, v1);
    }
    const float bbv = b1[c];
    const int row0 = rbase + r0;                     // even
    Uph[row0 * DHID + c]       = mk_h2(u0 + bbv, u0 + bbv);
    Uph[(row0 + 1) * DHID + c] = mk_h2(u1 + bbv, u1 + bbv);
    const h2 vp = mk_h2(v0, v1);
    const int jp = row0 >> 1;
    Vp2[jp * DHID + c]      = vp;
    Vp3[c * (BB / 2) + jp]  = vp;   // small scattered store, 256 KB total
}

// K2: per-channel sum / sumsq of relu(U[i,c] + V[j,c]), packed fp16.
// Grid: dim3(128, 8) = 1024 blocks, 4 blocks/CU. Block = 8 i x 64 jpairs.
// Thread: 4 channels x 8 u-rows in registers, jpair-stride-8 lane.
// Round-13 inner: pk_add + pk_max + pk_add(acc) + dot2(r,r) = 13 instr
// per (t,ii) incl. flush amortization (was 16): the plain-sum dot2 is
// replaced by an fp16 partial accumulator flushed via one dot2 per t.
__global__ __launch_bounds__(256, 4) void k2_stats(
    const h2* __restrict__ Uph, const h2* __restrict__ Vp2,
    float* __restrict__ partial)
{
    const int c0  = (threadIdx.x & 31) * 4;   // channel group
    const int jl  = threadIdx.x >> 5;         // 0..7
    const int ib  = blockIdx.x * 8;           // 8 i's  (gridDim.x = 128)
    const int jpb = blockIdx.y * 64;          // 64 jpairs (gridDim.y = 8)

    H24 u[8];
    #pragma unroll
    for (int ii = 0; ii < 8; ++ii)
        u[ii] = *(const H24*)&Uph[(ib + ii) * DHID + c0];   // 16B aligned

    float s0=0.f,s1=0.f,s2=0.f,s3=0.f, q0=0.f,q1=0.f,q2=0.f,q3=0.f;
    const h2 zero2 = mk_h2(0.f, 0.f);
    const h2 one2  = mk_h2(1.f, 1.f);
    const h2* vp = Vp2 + (jpb + jl) * DHID + c0;
    #pragma unroll
    for (int t = 0; t < 8; ++t) {
        const H24 v = *(const H24*)&vp[t * 8 * DHID];
        h2 aS0 = zero2, aS1 = zero2, aS2 = zero2, aS3 = zero2;
        #pragma unroll
        for (int ii = 0; ii < 8; ++ii) {
            h2 r;
            r = __builtin_elementwise_max(u[ii].h[0] + v.h[0], zero2);
            aS0 = aS0 + r; q0 = fdot2acc(r, r, q0);
            r = __builtin_elementwise_max(u[ii].h[1] + v.h[1], zero2);
            aS1 = aS1 + r; q1 = fdot2acc(r, r, q1);
            r = __builtin_elementwise_max(u[ii].h[2] + v.h[2], zero2);
            aS2 = aS2 + r; q2 = fdot2acc(r, r, q2);
            r = __builtin_elementwise_max(u[ii].h[3] + v.h[3], zero2);
            aS3 = aS3 + r; q3 = fdot2acc(r, r, q3);
        }
        // flush fp16 partial sums (<=8 values of <=~8 each: exact to 0.0625)
        s0 = fdot2acc(aS0, one2, s0);
        s1 = fdot2acc(aS1, one2, s1);
        s2 = fdot2acc(aS2, one2, s2);
        s3 = fdot2acc(aS3, one2, s3);
    }

    __shared__ float ls[8][DHID];
    __shared__ float lq[8][DHID];
    {
        float4 fs = {s0, s1, s2, s3};
        float4 fq = {q0, q1, q2, q3};
        *(float4*)&ls[jl][c0] = fs;
        *(float4*)&lq[jl][c0] = fq;
    }
    __syncthreads();

    if (threadIdx.x < 32) {
        float4 S = *(float4*)&ls[0][c0];
        float4 Q = *(float4*)&lq[0][c0];
        #pragma unroll
        for (int g = 1; g < 8; ++g) {
            S.x += ls[g][c0 + 0]; S.y += ls[g][c0 + 1];
            S.z += ls[g][c0 + 2]; S.w += ls[g][c0 + 3];
            Q.x += lq[g][c0 + 0]; Q.y += lq[g][c0 + 1];
            Q.z += lq[g][c0 + 2]; Q.w += lq[g][c0 + 3];
        }
        const int bid = blockIdx.y * 128 + blockIdx.x;   // 0..1023
        *(float4*)&partial[bid * 256 + c0]        = S;
        *(float4*)&partial[bid * 256 + DHID + c0] = Q;
    }
}

// K2b: reduce partial[1024][256] -> sums[256]. Plain stores, no atomics.
// Grid: 16 blocks x 256 threads, 16 columns per block.
__global__ __launch_bounds__(256) void k2b_reduce(
    const float* __restrict__ partial, float* __restrict__ sums)
{
    __shared__ float lred[16][17];
    const int cl   = threadIdx.x & 15;          // column-in-block
    const int rg   = threadIdx.x >> 4;          // 0..15 row group
    const int col  = blockIdx.x * 16 + cl;

    float acc = 0.f;
    #pragma unroll 8
    for (int t = 0; t < 64; ++t)
        acc += partial[(rg + 16 * t) * 256 + col];
    lred[rg][cl] = acc;
    __syncthreads();
    if (threadIdx.x < 16) {
        float a = 0.f;
        #pragma unroll
        for (int g = 0; g < 16; ++g) a += lred[g][threadIdx.x];
        sums[blockIdx.x * 16 + threadIdx.x] = a;
    }
}

// K3: out[i,j] = t + sum_c relu(U[i,c] + V[j,c]) * s[c], packed fp16.
// Grid: dim3(128, 8) = 1024 blocks, 4 blocks/CU. Block = 8 i x 128 j;
// thread = 2 i x 1 jpair (2 j). Inner per (i,jpair): pk_add+pk_max+pk_fma
// = 3 instr / 2 elements. fp16 accumulators flushed to fp32 every 32 c.
__global__ __launch_bounds__(256, 4) void k3_out(
    const h2* __restrict__ Uph, const h2* __restrict__ Vp3,
    const float* __restrict__ sums,
    const float* __restrict__ gamma, const float* __restrict__ beta,
    const float* __restrict__ W2, const float* __restrict__ b2,
    float* __restrict__ out)
{
    __shared__ __align__(16) h2 lutp[DHID][8];  // U packed, transposed [c][i]
    __shared__ h2    lsch[DHID];     // h2(s_c, s_c)
    __shared__ float ltp[DHID];
    __shared__ float lt;

    const int tid   = threadIdx.x;
    const int ib    = blockIdx.x * 8;     // gridDim.x = 128
    const int jbase = blockIdx.y * 128;   // gridDim.y = 8

    if (tid < DHID) {
        const float invN = 1.0f / NPAIRS;
        const float mean = sums[tid] * invN;
        const float var  = fmaxf(sums[DHID + tid] * invN - mean * mean, 0.f);
        const float inv  = rsqrtf(var + BN_EPS);
        const float gi   = gamma[tid] * inv;
        const float w2   = W2[tid];
        lsch[tid] = mk_h2(gi * w2, gi * w2);
        ltp[tid]  = (beta[tid] - mean * gi) * w2;
    }
    // stage 8 rows of packed U into LDS, transposed to [c][i]
    #pragma unroll
    for (int t = tid; t < 8 * DHID; t += 256)
        lutp[t & 127][t >> 7] = Uph[(ib + (t >> 7)) * DHID + (t & 127)];
    __syncthreads();
    // wave-0 shuffle reduction of ltp -> lt
    if (tid < 64) {
        float tl = ltp[tid] + ltp[tid + 64];
        #pragma unroll
        for (int off = 32; off >= 1; off >>= 1)
            tl += __shfl_down(tl, off, 64);
        if (tid == 0) lt = tl + b2[0];
    }
    __syncthreads();
    const float tconst = lt;

    const int i0   = (tid >> 6) * 2;              // 0,2,4,6 (wave-uniform)
    const int lane = tid & 63;
    const int jp0  = (jbase >> 1) + lane;         // 1 jpair = 2 j per lane

    const h2 zero2 = mk_h2(0.f, 0.f);
    h2 a00 = zero2, a10 = zero2;
    float2 f00 = {0.f, 0.f}, f10 = {0.f, 0.f};

    for (int cb = 0; cb < 4; ++cb) {
        #pragma unroll 8
        for (int ci = 0; ci < 32; ++ci) {
            const int c = cb * 32 + ci;
            const h2 v0  = Vp3[c * (BB / 2) + jp0];      // coalesced 4B/lane
            const h2 sc  = lsch[c];                      // LDS broadcast
            const H22 uu = *(const H22*)&lutp[c][i0];    // ONE ds_read_b64
            a00 = __builtin_elementwise_max(uu.lo + v0, zero2) * sc + a00;
            a10 = __builtin_elementwise_max(uu.hi + v0, zero2) * sc + a10;
        }
        f00.x += (float)a00.x; f00.y += (float)a00.y; a00 = zero2;
        f10.x += (float)a10.x; f10.y += (float)a10.y; a10 = zero2;
    }

    const int j0 = jbase + lane * 2;
    float2 o;
    o.x = f00.x + tconst; o.y = f00.y + tconst;
    *(float2*)&out[(ib + i0) * BB + j0] = o;
    o.x = f10.x + tconst; o.y = f10.y + tconst;
    *(float2*)&out[(ib + i0 + 1) * BB + j0] = o;
}

extern "C" void kernel_launch(void* const* d_in, const int* in_sizes, int n_in,
                              void* d_out, int out_size, void* d_ws, size_t ws_size,
                              hipStream_t stream) {
    const float* x     = (const float*)d_in[0];  // (1024, 64)
    const float* W1    = (const float*)d_in[1];  // (128, 128)
    const float* b1    = (const float*)d_in[2];  // (128,)
    const float* gamma = (const float*)d_in[3];  // (128,)
    const float* beta  = (const float*)d_in[4];  // (128,)
    const float* W2    = (const float*)d_in[5];  // (128,)
    const float* b2    = (const float*)d_in[6];  // (1,)
    float* out = (float*)d_out;                  // (1024*1024,)

    float* ws = (float*)d_ws;
    h2* Uph        = (h2*)ws;                    // 1024*128 h2 (512 KB)
    h2* Vp2        = (h2*)(ws + 131072);         // 512*128 h2 (256 KB)
    h2* Vp3        = (h2*)(ws + 196608);         // 128*512 h2 (256 KB)
    float* partial = ws + 262144;                // 1024*256 fp32 (1 MB)
    float* sums    = ws + 524288;                // 256 (sum | sumsq)

    k1_proj<<<256, 256, 0, stream>>>(x, W1, b1, Uph, Vp2, Vp3);
    k2_stats<<<dim3(128, 8), 256, 0, stream>>>(Uph, Vp2, partial);
    k2b_reduce<<<16, 256, 0, stream>>>(partial, sums);
    k3_out<<<dim3(128, 8), 256, 0, stream>>>(Uph, Vp3, sums, gamma, beta, W2, b2, out);
}